// Round 13
// baseline (470.966 us; speedup 1.0000x reference)
//
#include <hip/hip_runtime.h>

typedef __bf16 bf16x8 __attribute__((ext_vector_type(8)));
typedef __bf16 bf16x4 __attribute__((ext_vector_type(4)));
typedef float  floatx4 __attribute__((ext_vector_type(4)));

#define GLOBAL_AS __attribute__((address_space(1)))
#define LOCAL_AS  __attribute__((address_space(3)))

static constexpr int HID = 1024;
static constexpr int BK  = 64;        // K per tile
static constexpr int KIT = HID / BK;  // 16 K-tiles

__device__ __forceinline__ void h8(bf16x8& d, float s0, float s1,
                                   const float4& w0a, const float4& w0b,
                                   const float4& w1a, const float4& w1b,
                                   const float4& ba,  const float4& bb) {
    d[0] = (__bf16)fmaxf(fmaf(s1, w1a.x, fmaf(s0, w0a.x, ba.x)), 0.f);
    d[1] = (__bf16)fmaxf(fmaf(s1, w1a.y, fmaf(s0, w0a.y, ba.y)), 0.f);
    d[2] = (__bf16)fmaxf(fmaf(s1, w1a.z, fmaf(s0, w0a.z, ba.z)), 0.f);
    d[3] = (__bf16)fmaxf(fmaf(s1, w1a.w, fmaf(s0, w0a.w, ba.w)), 0.f);
    d[4] = (__bf16)fmaxf(fmaf(s1, w1b.x, fmaf(s0, w0b.x, bb.x)), 0.f);
    d[5] = (__bf16)fmaxf(fmaf(s1, w1b.y, fmaf(s0, w0b.y, bb.y)), 0.f);
    d[6] = (__bf16)fmaxf(fmaf(s1, w1b.z, fmaf(s0, w0b.z, bb.z)), 0.f);
    d[7] = (__bf16)fmaxf(fmaf(s1, w1b.w, fmaf(s0, w0b.w, bb.w)), 0.f);
}

// ---------------------------------------------------------------------------
// prep (r11 layouts, byte-identical):
//   [0,256)    zero OUT
//   [256,512)  W2 [K][N] fp32 -> W2T K-octet-major bf16:
//              W2T[(((slab*16+kt)*8+oct)*256+col)*8 + j]
//                = W2[kt*64+oct*8+j][slab*256+col]
//   [512,544)  W_heads -> WHT[(k>>3)*256 + r*8 + (k&7)], r=s*4+a (<20), else 0
// ---------------------------------------------------------------------------
__global__ __launch_bounds__(256)
void prep_all(const float* __restrict__ W2, const float* __restrict__ WH,
              __bf16* __restrict__ W2T, __bf16* __restrict__ WHT,
              float* __restrict__ OUT) {
    int b = blockIdx.x;
    if (b < 256) {
        ((float4*)OUT)[(size_t)b * 256 + threadIdx.x]
            = make_float4(0.f, 0.f, 0.f, 0.f);
        return;
    }
    b -= 256;
    if (b < 256) {
        __shared__ __align__(16) __bf16 tile[64][72];  // [col][k], 16B-aligned rows
        const int bx = b & 15;   // 64-col group
        const int by = b >> 4;   // 64-k group (= kt)
        const int a  = threadIdx.x & 63;
        const int bb = threadIdx.x >> 6;  // 0..3
#pragma unroll
        for (int r = 0; r < 16; ++r) {
            const int k = r * 4 + bb;
            tile[a][k] = (__bf16)W2[(size_t)(by * 64 + k) * HID + bx * 64 + a];
        }
        __syncthreads();
        const int slab = bx >> 2;
#pragma unroll
        for (int p = 0; p < 2; ++p) {
            const int idx = p * 256 + threadIdx.x;   // 0..511
            const int c   = idx & 63;
            const int oct = idx >> 6;                // 0..7
            const bf16x8 v = *(const bf16x8*)&tile[c][oct * 8];
            const int col = (bx & 3) * 64 + c;
            const size_t dst = ((size_t)(slab * KIT + by) * 8 + oct) * 256 + col;
            *(bf16x8*)(W2T + dst * 8) = v;
        }
    } else {
        const int r = b - 256;             // 0..31
        const int s = r >> 2, a = r & 3;
        for (int k = threadIdx.x; k < HID; k += 256) {
            const float v = (r < 20) ? WH[((size_t)s * HID + k) * 4 + a] : 0.f;
            WHT[(size_t)(k >> 3) * 256 + r * 8 + (k & 7)] = (__bf16)v;
        }
    }
}

// ---------------------------------------------------------------------------
// r11 champion (direct-wf, single barrier/tile, 32 KiB LDS, 165 us main)
// with ONE change: __launch_bounds__(256, 3) -> (256, 4).
// Diagnosis: every pipe (MFMA 38%, VALU 36%, DS ~31%, L2 ~37%) sits at
// ~35-40% -- the signature of latency-bound execution at ~3 waves/SIMD
// (VGPR 80 + 64 AGPR = 144 regs/wave -> 512/144 = 3). Capping at 128 regs
// (64 arch + 64 acc) steps occupancy to 4 waves/SIMD (+33% wave diversity).
// r4's near-identical body fit 64 arch VGPRs, so a clean fit is plausible;
// abort-check is WRITE_SIZE (spill) > 20 MB.
// ---------------------------------------------------------------------------
__global__ __launch_bounds__(256, 4)
void policy_main(const float* __restrict__ S,  const int* __restrict__ SK,
                 const float* __restrict__ W1, const float* __restrict__ B1,
                 const __bf16* __restrict__ W2T, const float* __restrict__ B2,
                 const __bf16* __restrict__ WHT, const float* __restrict__ BH,
                 float* __restrict__ OUT) {
    __shared__ __align__(16) char smem[32768];
    __bf16* At    = (__bf16*)smem;            // 2 x [8 oct][64 smp][8] = 16 KiB
    __bf16* featL = (__bf16*)smem;            // overlay [32 oct][64 smp][8] = 32K

    const int tid  = threadIdx.x;
    const int lane = tid & 63;
    const int wv   = tid >> 6;       // 0..3  (featcol strip of 64)
    const int l15  = lane & 15;
    const int quad = lane >> 4;
    const int slab = blockIdx.x >> 10;      // 0..3 (256-col slab)
    const int g    = blockIdx.x & 1023;     // sample group
    const size_t i0 = (size_t)g * 64;

    const int octA = wv * 2 + (lane >> 5);  // A-compute k-octet
    const int smpA = lane & 31;             // A-compute sample

    floatx4 acc[4][4] = {};   // [fn featcol-frag][fm sample-frag]

    // ---- prologue: this lane's 2 sample states
    const float2 sv0 = *(const float2*)(S + (i0 + smpA) * 2);
    const float2 sv1 = *(const float2*)(S + (i0 + 32 + smpA) * 2);

    // ---- prologue: compute A[0] -> At buf 0
    {
        const float* wp = W1 + octA * 8;
        const float4 w0a = *(const float4*)(wp);
        const float4 w0b = *(const float4*)(wp + 4);
        const float4 w1a = *(const float4*)(wp + HID);
        const float4 w1b = *(const float4*)(wp + HID + 4);
        const float4 ba  = *(const float4*)(B1 + octA * 8);
        const float4 bb  = *(const float4*)(B1 + octA * 8 + 4);
        bf16x8 hv;
        h8(hv, sv0.x, sv0.y, w0a, w0b, w1a, w1b, ba, bb);
        *(bf16x8*)(At + (octA * 64 + smpA) * 8) = hv;
        h8(hv, sv1.x, sv1.y, w0a, w0b, w1a, w1b, ba, bb);
        *(bf16x8*)(At + (octA * 64 + 32 + smpA) * 8) = hv;
    }
    __syncthreads();   // At[0] visible

    // per-lane W2T fragment base: octet o reads at +o*2048 elems, ks at quad
    const __bf16* wbase = W2T + ((size_t)(slab * KIT) * 8 + quad) * 2048
                        + (wv * 64 + l15) * 8;

#pragma unroll 1
    for (int kt = 0; kt < KIT; ++kt) {
        const __bf16* Ac = At + (kt & 1) * 4096;
        __bf16*       An = At + ((kt + 1) & 1) * 4096;

        // ---- W1/B1 loads for NEXT tile first (oldest in vm queue)
        float4 w0a, w0b, w1a, w1b, ba, bb;
        if (kt + 1 < KIT) {
            const float* wp = W1 + (kt + 1) * BK + octA * 8;
            w0a = *(const float4*)(wp);
            w0b = *(const float4*)(wp + 4);
            w1a = *(const float4*)(wp + HID);
            w1b = *(const float4*)(wp + HID + 4);
            ba  = *(const float4*)(B1 + (kt + 1) * BK + octA * 8);
            bb  = *(const float4*)(B1 + (kt + 1) * BK + octA * 8 + 4);
        }
        // ---- wf: 8 direct global loads from W2T (L2-hot), issued early
        bf16x8 wf0[4], wf1[4];
        const __bf16* wkt = wbase + (size_t)kt * 8 * 2048;
#pragma unroll
        for (int f = 0; f < 4; ++f)
            wf0[f] = *(const bf16x8*)(wkt + f * 16 * 8);                 // ks=0
#pragma unroll
        for (int f = 0; f < 4; ++f)
            wf1[f] = *(const bf16x8*)(wkt + 4 * 2048 + f * 16 * 8);      // ks=1
        // ---- h8 -> At[nxt] (waits only on W1: vmcnt leaves wf in flight)
        if (kt + 1 < KIT) {
            bf16x8 hv;
            h8(hv, sv0.x, sv0.y, w0a, w0b, w1a, w1b, ba, bb);
            *(bf16x8*)(An + (octA * 64 + smpA) * 8) = hv;
            h8(hv, sv1.x, sv1.y, w0a, w0b, w1a, w1b, ba, bb);
            *(bf16x8*)(An + (octA * 64 + 32 + smpA) * 8) = hv;
        }
        // ---- ks=0: 4 hf ds_reads + 16 MFMA
        {
            bf16x8 hf[4];
#pragma unroll
            for (int f = 0; f < 4; ++f)
                hf[f] = *(const bf16x8*)(Ac + ((quad * 64) + f * 16 + l15) * 8);
#pragma unroll
            for (int fn = 0; fn < 4; ++fn)
#pragma unroll
                for (int fm = 0; fm < 4; ++fm)
                    acc[fn][fm] = __builtin_amdgcn_mfma_f32_16x16x32_bf16(
                        wf0[fn], hf[fm], acc[fn][fm], 0, 0, 0);
        }
        // ---- ks=1
        {
            bf16x8 hf[4];
#pragma unroll
            for (int f = 0; f < 4; ++f)
                hf[f] = *(const bf16x8*)(Ac + (((4 + quad) * 64) + f * 16 + l15) * 8);
#pragma unroll
            for (int fn = 0; fn < 4; ++fn)
#pragma unroll
                for (int fm = 0; fm < 4; ++fm)
                    acc[fn][fm] = __builtin_amdgcn_mfma_f32_16x16x32_bf16(
                        wf1[fn], hf[fm], acc[fn][fm], 0, 0, 0);
        }
        __syncthreads();   // At[nxt] visible; all At[cur] reads done. VMEM
                           // already consumed -> the vmcnt(0) drain is free.
    }

    // ---- epilogue: relu(acc + b2) -> featL (overlay over At, 32 KiB)
#pragma unroll
    for (int fn = 0; fn < 4; ++fn) {
        const int fcb = wv * 64 + fn * 16 + quad * 4;   // featcol base
        const float4 b2v = *(const float4*)(B2 + slab * 256 + fcb);
        const int o = fcb >> 3, j = fcb & 7;
#pragma unroll
        for (int fm = 0; fm < 4; ++fm) {
            const int smp = fm * 16 + l15;
            const floatx4 v = acc[fn][fm];
            bf16x4 p;
            p[0] = (__bf16)fmaxf(v[0] + b2v.x, 0.f);
            p[1] = (__bf16)fmaxf(v[1] + b2v.y, 0.f);
            p[2] = (__bf16)fmaxf(v[2] + b2v.z, 0.f);
            p[3] = (__bf16)fmaxf(v[3] + b2v.w, 0.f);
            *(bf16x4*)(featL + (o * 64 + smp) * 8 + j) = p;
        }
    }
    __syncthreads();

    // ---- head MFMA: wave wv -> samples wv*16..+15; WHT direct (L2-hot)
    floatx4 hacc[2] = {};
#pragma unroll
    for (int ks2 = 0; ks2 < 8; ++ks2) {
        const bf16x8 fa = *(const bf16x8*)(featL
                             + ((ks2 * 4 + quad) * 64 + wv * 16 + l15) * 8);
#pragma unroll
        for (int t2 = 0; t2 < 2; ++t2) {
            const int r  = t2 * 16 + l15;
            const int og = slab * 32 + ks2 * 4 + quad;
            const bf16x8 wb = *(const bf16x8*)(WHT + (size_t)og * 256 + r * 8);
            hacc[t2] = __builtin_amdgcn_mfma_f32_16x16x32_bf16(
                fa, wb, hacc[t2], 0, 0, 0);
        }
    }

    // ---- atomic scatter: sample = quad*4+reg; emit selected skill's 4 actions
#pragma unroll
    for (int j = 0; j < 4; ++j) {
        const int smp = wv * 16 + quad * 4 + j;
        const int sk  = SK[i0 + smp];
#pragma unroll
        for (int t2 = 0; t2 < 2; ++t2) {
            const int hc = t2 * 16 + l15;
            const int d  = hc - sk * 4;
            if (d >= 0 && d < 4) {
                float v = hacc[t2][j];
                if (slab == 0) v += BH[hc];
                atomicAdd(&OUT[(i0 + smp) * 4 + d], v);
            }
        }
    }
}

extern "C" void kernel_launch(void* const* d_in, const int* in_sizes, int n_in,
                              void* d_out, int out_size, void* d_ws, size_t ws_size,
                              hipStream_t stream) {
    const float* S  = (const float*)d_in[0];
    const int*   SK = (const int*)d_in[1];
    const float* W1 = (const float*)d_in[2];
    const float* B1 = (const float*)d_in[3];
    const float* W2 = (const float*)d_in[4];
    const float* B2 = (const float*)d_in[5];
    const float* WH = (const float*)d_in[6];
    const float* BH = (const float*)d_in[7];

    char* ws = (char*)d_ws;
    __bf16* W2T = (__bf16*)ws;                          // 2 MiB
    __bf16* WHT = (__bf16*)(ws + 2 * 1024 * 1024);      // 64 KiB

    hipLaunchKernelGGL(prep_all, dim3(544), dim3(256), 0, stream,
                       W2, WH, W2T, WHT, (float*)d_out);
    // grid: 1024 sample-groups x 4 slabs; slab = blockIdx>>10 so co-resident
    // blocks share one W2T slab (L2-friendly)
    hipLaunchKernelGGL(policy_main, dim3(4096), dim3(256), 0, stream,
                       S, SK, W1, B1, W2T, B2, WHT, BH, (float*)d_out);
}

// Round 14
// 297.223 us; speedup vs baseline: 1.5846x; 1.5846x over previous
//
#include <hip/hip_runtime.h>

typedef __bf16 bf16x8 __attribute__((ext_vector_type(8)));
typedef __bf16 bf16x4 __attribute__((ext_vector_type(4)));
typedef float  floatx4 __attribute__((ext_vector_type(4)));

#define GLOBAL_AS __attribute__((address_space(1)))
#define LOCAL_AS  __attribute__((address_space(3)))

static constexpr int HID = 1024;
static constexpr int BK  = 64;        // K per tile
static constexpr int KIT = HID / BK;  // 16 K-tiles

__device__ __forceinline__ void h8(bf16x8& d, float s0, float s1,
                                   const float4& w0a, const float4& w0b,
                                   const float4& w1a, const float4& w1b,
                                   const float4& ba,  const float4& bb) {
    d[0] = (__bf16)fmaxf(fmaf(s1, w1a.x, fmaf(s0, w0a.x, ba.x)), 0.f);
    d[1] = (__bf16)fmaxf(fmaf(s1, w1a.y, fmaf(s0, w0a.y, ba.y)), 0.f);
    d[2] = (__bf16)fmaxf(fmaf(s1, w1a.z, fmaf(s0, w0a.z, ba.z)), 0.f);
    d[3] = (__bf16)fmaxf(fmaf(s1, w1a.w, fmaf(s0, w0a.w, ba.w)), 0.f);
    d[4] = (__bf16)fmaxf(fmaf(s1, w1b.x, fmaf(s0, w0b.x, bb.x)), 0.f);
    d[5] = (__bf16)fmaxf(fmaf(s1, w1b.y, fmaf(s0, w0b.y, bb.y)), 0.f);
    d[6] = (__bf16)fmaxf(fmaf(s1, w1b.z, fmaf(s0, w0b.z, bb.z)), 0.f);
    d[7] = (__bf16)fmaxf(fmaf(s1, w1b.w, fmaf(s0, w0b.w, bb.w)), 0.f);
}

// ---------------------------------------------------------------------------
// prep (r11 layouts, byte-identical):
//   [0,256)    zero OUT
//   [256,512)  W2 [K][N] fp32 -> W2T K-octet-major bf16:
//              W2T[(((slab*16+kt)*8+oct)*256+col)*8 + j]
//                = W2[kt*64+oct*8+j][slab*256+col]
//   [512,544)  W_heads -> WHT[(k>>3)*256 + r*8 + (k&7)], r=s*4+a (<20), else 0
// ---------------------------------------------------------------------------
__global__ __launch_bounds__(256)
void prep_all(const float* __restrict__ W2, const float* __restrict__ WH,
              __bf16* __restrict__ W2T, __bf16* __restrict__ WHT,
              float* __restrict__ OUT) {
    int b = blockIdx.x;
    if (b < 256) {
        ((float4*)OUT)[(size_t)b * 256 + threadIdx.x]
            = make_float4(0.f, 0.f, 0.f, 0.f);
        return;
    }
    b -= 256;
    if (b < 256) {
        __shared__ __align__(16) __bf16 tile[64][72];  // [col][k], 16B-aligned rows
        const int bx = b & 15;   // 64-col group
        const int by = b >> 4;   // 64-k group (= kt)
        const int a  = threadIdx.x & 63;
        const int bb = threadIdx.x >> 6;  // 0..3
#pragma unroll
        for (int r = 0; r < 16; ++r) {
            const int k = r * 4 + bb;
            tile[a][k] = (__bf16)W2[(size_t)(by * 64 + k) * HID + bx * 64 + a];
        }
        __syncthreads();
        const int slab = bx >> 2;
#pragma unroll
        for (int p = 0; p < 2; ++p) {
            const int idx = p * 256 + threadIdx.x;   // 0..511
            const int c   = idx & 63;
            const int oct = idx >> 6;                // 0..7
            const bf16x8 v = *(const bf16x8*)&tile[c][oct * 8];
            const int col = (bx & 3) * 64 + c;
            const size_t dst = ((size_t)(slab * KIT + by) * 8 + oct) * 256 + col;
            *(bf16x8*)(W2T + dst * 8) = v;
        }
    } else {
        const int r = b - 256;             // 0..31
        const int s = r >> 2, a = r & 3;
        for (int k = threadIdx.x; k < HID; k += 256) {
            const float v = (r < 20) ? WH[((size_t)s * HID + k) * 4 + a] : 0.f;
            WHT[(size_t)(k >> 3) * 256 + r * 8 + (k & 7)] = (__bf16)v;
        }
    }
}

// ---------------------------------------------------------------------------
// r11 champion (direct-wf, single barrier/tile, 32 KiB LDS) made to FIT the
// 4-wave register budget. r13 taught: bounds(256,4) caps arch VGPR at 64
// (64 arch + 64 AGPR acc = 128 = 512/4), and r11's body demands 80 -> 16
// spilled regs, 790 MB of scratch traffic. The 16-reg excess is wf0+wf1
// (32 VGPRs of W2T fragments) held live across BOTH k-steps. Fix: load wf
// PER K-STEP (r4's body shape, which measured exactly 64 arch VGPRs):
//   tile kt: {W1[kt+1] loads, wf0 loads, h8 -> An (wf0 in flight),
//             ks0 MFMA (waits wf0), wf1 loads, ks1 MFMA, barrier}.
// wf1's ~200-cyc L2 latency hides under ks0's 16-MFMA chain + 4-wave TLP.
// LDS 32K x 4 blocks = 128K fits. Abort-check: WRITE_SIZE > 20 MB = spill.
// ---------------------------------------------------------------------------
__global__ __launch_bounds__(256, 4)
void policy_main(const float* __restrict__ S,  const int* __restrict__ SK,
                 const float* __restrict__ W1, const float* __restrict__ B1,
                 const __bf16* __restrict__ W2T, const float* __restrict__ B2,
                 const __bf16* __restrict__ WHT, const float* __restrict__ BH,
                 float* __restrict__ OUT) {
    __shared__ __align__(16) char smem[32768];
    __bf16* At    = (__bf16*)smem;            // 2 x [8 oct][64 smp][8] = 16 KiB
    __bf16* featL = (__bf16*)smem;            // overlay [32 oct][64 smp][8] = 32K

    const int tid  = threadIdx.x;
    const int lane = tid & 63;
    const int wv   = tid >> 6;       // 0..3  (featcol strip of 64)
    const int l15  = lane & 15;
    const int quad = lane >> 4;
    const int slab = blockIdx.x >> 10;      // 0..3 (256-col slab)
    const int g    = blockIdx.x & 1023;     // sample group
    const size_t i0 = (size_t)g * 64;

    const int octA = wv * 2 + (lane >> 5);  // A-compute k-octet
    const int smpA = lane & 31;             // A-compute sample

    floatx4 acc[4][4] = {};   // [fn featcol-frag][fm sample-frag]

    // ---- prologue: this lane's 2 sample states
    const float2 sv0 = *(const float2*)(S + (i0 + smpA) * 2);
    const float2 sv1 = *(const float2*)(S + (i0 + 32 + smpA) * 2);

    // ---- prologue: compute A[0] -> At buf 0
    {
        const float* wp = W1 + octA * 8;
        const float4 w0a = *(const float4*)(wp);
        const float4 w0b = *(const float4*)(wp + 4);
        const float4 w1a = *(const float4*)(wp + HID);
        const float4 w1b = *(const float4*)(wp + HID + 4);
        const float4 ba  = *(const float4*)(B1 + octA * 8);
        const float4 bb  = *(const float4*)(B1 + octA * 8 + 4);
        bf16x8 hv;
        h8(hv, sv0.x, sv0.y, w0a, w0b, w1a, w1b, ba, bb);
        *(bf16x8*)(At + (octA * 64 + smpA) * 8) = hv;
        h8(hv, sv1.x, sv1.y, w0a, w0b, w1a, w1b, ba, bb);
        *(bf16x8*)(At + (octA * 64 + 32 + smpA) * 8) = hv;
    }
    __syncthreads();   // At[0] visible

    // per-lane W2T fragment base: octet o reads at +o*2048 elems, ks at quad
    const __bf16* wbase = W2T + ((size_t)(slab * KIT) * 8 + quad) * 2048
                        + (wv * 64 + l15) * 8;

#pragma unroll 1
    for (int kt = 0; kt < KIT; ++kt) {
        const __bf16* Ac = At + (kt & 1) * 4096;
        __bf16*       An = At + ((kt + 1) & 1) * 4096;
        const __bf16* wkt = wbase + (size_t)kt * 8 * 2048;

        // ---- W1/B1 loads for NEXT tile first (oldest in vm queue)
        float4 w0a, w0b, w1a, w1b, ba, bb;
        if (kt + 1 < KIT) {
            const float* wp = W1 + (kt + 1) * BK + octA * 8;
            w0a = *(const float4*)(wp);
            w0b = *(const float4*)(wp + 4);
            w1a = *(const float4*)(wp + HID);
            w1b = *(const float4*)(wp + HID + 4);
            ba  = *(const float4*)(B1 + (kt + 1) * BK + octA * 8);
            bb  = *(const float4*)(B1 + (kt + 1) * BK + octA * 8 + 4);
        }
        // ---- ks=0 wf loads (in flight under h8)
        {
            bf16x8 wf[4], hf[4];
#pragma unroll
            for (int f = 0; f < 4; ++f)
                wf[f] = *(const bf16x8*)(wkt + f * 16 * 8);
            // ---- h8 -> At[nxt] (waits only on W1; wf stays in flight)
            if (kt + 1 < KIT) {
                bf16x8 hv;
                h8(hv, sv0.x, sv0.y, w0a, w0b, w1a, w1b, ba, bb);
                *(bf16x8*)(An + (octA * 64 + smpA) * 8) = hv;
                h8(hv, sv1.x, sv1.y, w0a, w0b, w1a, w1b, ba, bb);
                *(bf16x8*)(An + (octA * 64 + 32 + smpA) * 8) = hv;
            }
#pragma unroll
            for (int f = 0; f < 4; ++f)
                hf[f] = *(const bf16x8*)(Ac + ((quad * 64) + f * 16 + l15) * 8);
#pragma unroll
            for (int fn = 0; fn < 4; ++fn)
#pragma unroll
                for (int fm = 0; fm < 4; ++fm)
                    acc[fn][fm] = __builtin_amdgcn_mfma_f32_16x16x32_bf16(
                        wf[fn], hf[fm], acc[fn][fm], 0, 0, 0);
        }
        // ---- ks=1 (wf loaded here; L2 latency hides under ks0 MFMAs + TLP)
        {
            bf16x8 wf[4], hf[4];
#pragma unroll
            for (int f = 0; f < 4; ++f)
                wf[f] = *(const bf16x8*)(wkt + 4 * 2048 + f * 16 * 8);
#pragma unroll
            for (int f = 0; f < 4; ++f)
                hf[f] = *(const bf16x8*)(Ac + (((4 + quad) * 64) + f * 16 + l15) * 8);
#pragma unroll
            for (int fn = 0; fn < 4; ++fn)
#pragma unroll
                for (int fm = 0; fm < 4; ++fm)
                    acc[fn][fm] = __builtin_amdgcn_mfma_f32_16x16x32_bf16(
                        wf[fn], hf[fm], acc[fn][fm], 0, 0, 0);
        }
        __syncthreads();   // At[nxt] visible; all At[cur] reads done
    }

    // ---- epilogue: relu(acc + b2) -> featL (overlay over At, 32 KiB)
#pragma unroll
    for (int fn = 0; fn < 4; ++fn) {
        const int fcb = wv * 64 + fn * 16 + quad * 4;   // featcol base
        const float4 b2v = *(const float4*)(B2 + slab * 256 + fcb);
        const int o = fcb >> 3, j = fcb & 7;
#pragma unroll
        for (int fm = 0; fm < 4; ++fm) {
            const int smp = fm * 16 + l15;
            const floatx4 v = acc[fn][fm];
            bf16x4 p;
            p[0] = (__bf16)fmaxf(v[0] + b2v.x, 0.f);
            p[1] = (__bf16)fmaxf(v[1] + b2v.y, 0.f);
            p[2] = (__bf16)fmaxf(v[2] + b2v.z, 0.f);
            p[3] = (__bf16)fmaxf(v[3] + b2v.w, 0.f);
            *(bf16x4*)(featL + (o * 64 + smp) * 8 + j) = p;
        }
    }
    __syncthreads();

    // ---- head MFMA: wave wv -> samples wv*16..+15; WHT direct (L2-hot)
    floatx4 hacc[2] = {};
#pragma unroll
    for (int ks2 = 0; ks2 < 8; ++ks2) {
        const bf16x8 fa = *(const bf16x8*)(featL
                             + ((ks2 * 4 + quad) * 64 + wv * 16 + l15) * 8);
#pragma unroll
        for (int t2 = 0; t2 < 2; ++t2) {
            const int r  = t2 * 16 + l15;
            const int og = slab * 32 + ks2 * 4 + quad;
            const bf16x8 wb = *(const bf16x8*)(WHT + (size_t)og * 256 + r * 8);
            hacc[t2] = __builtin_amdgcn_mfma_f32_16x16x32_bf16(
                fa, wb, hacc[t2], 0, 0, 0);
        }
    }

    // ---- atomic scatter: sample = quad*4+reg; emit selected skill's 4 actions
#pragma unroll
    for (int j = 0; j < 4; ++j) {
        const int smp = wv * 16 + quad * 4 + j;
        const int sk  = SK[i0 + smp];
#pragma unroll
        for (int t2 = 0; t2 < 2; ++t2) {
            const int hc = t2 * 16 + l15;
            const int d  = hc - sk * 4;
            if (d >= 0 && d < 4) {
                float v = hacc[t2][j];
                if (slab == 0) v += BH[hc];
                atomicAdd(&OUT[(i0 + smp) * 4 + d], v);
            }
        }
    }
}

extern "C" void kernel_launch(void* const* d_in, const int* in_sizes, int n_in,
                              void* d_out, int out_size, void* d_ws, size_t ws_size,
                              hipStream_t stream) {
    const float* S  = (const float*)d_in[0];
    const int*   SK = (const int*)d_in[1];
    const float* W1 = (const float*)d_in[2];
    const float* B1 = (const float*)d_in[3];
    const float* W2 = (const float*)d_in[4];
    const float* B2 = (const float*)d_in[5];
    const float* WH = (const float*)d_in[6];
    const float* BH = (const float*)d_in[7];

    char* ws = (char*)d_ws;
    __bf16* W2T = (__bf16*)ws;                          // 2 MiB
    __bf16* WHT = (__bf16*)(ws + 2 * 1024 * 1024);      // 64 KiB

    hipLaunchKernelGGL(prep_all, dim3(544), dim3(256), 0, stream,
                       W2, WH, W2T, WHT, (float*)d_out);
    // grid: 1024 sample-groups x 4 slabs; slab = blockIdx>>10 so co-resident
    // blocks share one W2T slab (L2-friendly)
    hipLaunchKernelGGL(policy_main, dim3(4096), dim3(256), 0, stream,
                       S, SK, W1, B1, W2T, B2, WHT, BH, (float*)d_out);
}

// Round 15
// 224.713 us; speedup vs baseline: 2.0959x; 1.3227x over previous
//
#include <hip/hip_runtime.h>

typedef __bf16 bf16x8 __attribute__((ext_vector_type(8)));
typedef __bf16 bf16x4 __attribute__((ext_vector_type(4)));
typedef float  floatx4 __attribute__((ext_vector_type(4)));

#define GLOBAL_AS __attribute__((address_space(1)))
#define LOCAL_AS  __attribute__((address_space(3)))

static constexpr int HID = 1024;
static constexpr int BK  = 64;        // K per tile
static constexpr int KIT = HID / BK;  // 16 K-tiles

__device__ __forceinline__ void h8(bf16x8& d, float s0, float s1,
                                   const float4& w0a, const float4& w0b,
                                   const float4& w1a, const float4& w1b,
                                   const float4& ba,  const float4& bb) {
    d[0] = (__bf16)fmaxf(fmaf(s1, w1a.x, fmaf(s0, w0a.x, ba.x)), 0.f);
    d[1] = (__bf16)fmaxf(fmaf(s1, w1a.y, fmaf(s0, w0a.y, ba.y)), 0.f);
    d[2] = (__bf16)fmaxf(fmaf(s1, w1a.z, fmaf(s0, w0a.z, ba.z)), 0.f);
    d[3] = (__bf16)fmaxf(fmaf(s1, w1a.w, fmaf(s0, w0a.w, ba.w)), 0.f);
    d[4] = (__bf16)fmaxf(fmaf(s1, w1b.x, fmaf(s0, w0b.x, bb.x)), 0.f);
    d[5] = (__bf16)fmaxf(fmaf(s1, w1b.y, fmaf(s0, w0b.y, bb.y)), 0.f);
    d[6] = (__bf16)fmaxf(fmaf(s1, w1b.z, fmaf(s0, w0b.z, bb.z)), 0.f);
    d[7] = (__bf16)fmaxf(fmaf(s1, w1b.w, fmaf(s0, w0b.w, bb.w)), 0.f);
}

// ---------------------------------------------------------------------------
// prep (r11 layouts, byte-identical):
//   [0,256)    zero OUT
//   [256,512)  W2 [K][N] fp32 -> W2T K-octet-major bf16:
//              W2T[(((slab*16+kt)*8+oct)*256+col)*8 + j]
//                = W2[kt*64+oct*8+j][slab*256+col]
//   [512,544)  W_heads -> WHT[(k>>3)*256 + r*8 + (k&7)], r=s*4+a (<20), else 0
// ---------------------------------------------------------------------------
__global__ __launch_bounds__(256)
void prep_all(const float* __restrict__ W2, const float* __restrict__ WH,
              __bf16* __restrict__ W2T, __bf16* __restrict__ WHT,
              float* __restrict__ OUT) {
    int b = blockIdx.x;
    if (b < 256) {
        ((float4*)OUT)[(size_t)b * 256 + threadIdx.x]
            = make_float4(0.f, 0.f, 0.f, 0.f);
        return;
    }
    b -= 256;
    if (b < 256) {
        __shared__ __align__(16) __bf16 tile[64][72];  // [col][k], 16B-aligned rows
        const int bx = b & 15;   // 64-col group
        const int by = b >> 4;   // 64-k group (= kt)
        const int a  = threadIdx.x & 63;
        const int bb = threadIdx.x >> 6;  // 0..3
#pragma unroll
        for (int r = 0; r < 16; ++r) {
            const int k = r * 4 + bb;
            tile[a][k] = (__bf16)W2[(size_t)(by * 64 + k) * HID + bx * 64 + a];
        }
        __syncthreads();
        const int slab = bx >> 2;
#pragma unroll
        for (int p = 0; p < 2; ++p) {
            const int idx = p * 256 + threadIdx.x;   // 0..511
            const int c   = idx & 63;
            const int oct = idx >> 6;                // 0..7
            const bf16x8 v = *(const bf16x8*)&tile[c][oct * 8];
            const int col = (bx & 3) * 64 + c;
            const size_t dst = ((size_t)(slab * KIT + by) * 8 + oct) * 256 + col;
            *(bf16x8*)(W2T + dst * 8) = v;
        }
    } else {
        const int r = b - 256;             // 0..31
        const int s = r >> 2, a = r & 3;
        for (int k = threadIdx.x; k < HID; k += 256) {
            const float v = (r < 20) ? WH[((size_t)s * HID + k) * 4 + a] : 0.f;
            WHT[(size_t)(k >> 3) * 256 + r * 8 + (k & 7)] = (__bf16)v;
        }
    }
}

// ---------------------------------------------------------------------------
// CHAMPION (r11, 165.4 us main / 215.6 us total): direct-wf GEMM + fused
// layer-1 + fused head. Reverted to byte-identical after r12-r14 regressions.
//   - layer-1 (H = relu(s@W1+b1)) computed in-register per tile -> At dbuf
//     (H never materialized in HBM; r1's win).
//   - B operand (W2T, L2-hot) read DIRECTLY into wf registers -- no LDS
//     staging: each element is used once, so staging bought nothing (r11's
//     win; deleted 62% of DS traffic + one barrier/tile).
//   - single __syncthreads per tile; W1 loads issued oldest so h8 waits
//     vmcnt(8) and wf stays in flight under it.
//   - head: featL overlay + WHT direct, atomic scatter of the selected
//     skill's 4 actions.
// Plateau evidence: MFMA 38 / VALU 36 / DS ~31 / L2 ~37 / HBM 1.3%, and ten
// counter-refuted restructurings (8-phase, reg/LDS W1 pipelining, 8-block
// occupancy, single-writer, 4-wave caps) all at or below this point. The
// binding constraint is 64 AGPR acc + ~80 arch VGPR -> 3 waves/SIMD;
// every attempt to exceed it spilled (r7/r13/r14) or lost overlap (r12).
// ---------------------------------------------------------------------------
__global__ __launch_bounds__(256, 3)
void policy_main(const float* __restrict__ S,  const int* __restrict__ SK,
                 const float* __restrict__ W1, const float* __restrict__ B1,
                 const __bf16* __restrict__ W2T, const float* __restrict__ B2,
                 const __bf16* __restrict__ WHT, const float* __restrict__ BH,
                 float* __restrict__ OUT) {
    __shared__ __align__(16) char smem[32768];
    __bf16* At    = (__bf16*)smem;            // 2 x [8 oct][64 smp][8] = 16 KiB
    __bf16* featL = (__bf16*)smem;            // overlay [32 oct][64 smp][8] = 32K

    const int tid  = threadIdx.x;
    const int lane = tid & 63;
    const int wv   = tid >> 6;       // 0..3  (featcol strip of 64)
    const int l15  = lane & 15;
    const int quad = lane >> 4;
    const int slab = blockIdx.x >> 10;      // 0..3 (256-col slab)
    const int g    = blockIdx.x & 1023;     // sample group
    const size_t i0 = (size_t)g * 64;

    const int octA = wv * 2 + (lane >> 5);  // A-compute k-octet
    const int smpA = lane & 31;             // A-compute sample

    floatx4 acc[4][4] = {};   // [fn featcol-frag][fm sample-frag]

    // ---- prologue: this lane's 2 sample states
    const float2 sv0 = *(const float2*)(S + (i0 + smpA) * 2);
    const float2 sv1 = *(const float2*)(S + (i0 + 32 + smpA) * 2);

    // ---- prologue: compute A[0] -> At buf 0
    {
        const float* wp = W1 + octA * 8;
        const float4 w0a = *(const float4*)(wp);
        const float4 w0b = *(const float4*)(wp + 4);
        const float4 w1a = *(const float4*)(wp + HID);
        const float4 w1b = *(const float4*)(wp + HID + 4);
        const float4 ba  = *(const float4*)(B1 + octA * 8);
        const float4 bb  = *(const float4*)(B1 + octA * 8 + 4);
        bf16x8 hv;
        h8(hv, sv0.x, sv0.y, w0a, w0b, w1a, w1b, ba, bb);
        *(bf16x8*)(At + (octA * 64 + smpA) * 8) = hv;
        h8(hv, sv1.x, sv1.y, w0a, w0b, w1a, w1b, ba, bb);
        *(bf16x8*)(At + (octA * 64 + 32 + smpA) * 8) = hv;
    }
    __syncthreads();   // At[0] visible

    // per-lane W2T fragment base: octet o reads at +o*2048 elems, ks at quad
    const __bf16* wbase = W2T + ((size_t)(slab * KIT) * 8 + quad) * 2048
                        + (wv * 64 + l15) * 8;

#pragma unroll 1
    for (int kt = 0; kt < KIT; ++kt) {
        const __bf16* Ac = At + (kt & 1) * 4096;
        __bf16*       An = At + ((kt + 1) & 1) * 4096;

        // ---- W1/B1 loads for NEXT tile first (oldest in vm queue)
        float4 w0a, w0b, w1a, w1b, ba, bb;
        if (kt + 1 < KIT) {
            const float* wp = W1 + (kt + 1) * BK + octA * 8;
            w0a = *(const float4*)(wp);
            w0b = *(const float4*)(wp + 4);
            w1a = *(const float4*)(wp + HID);
            w1b = *(const float4*)(wp + HID + 4);
            ba  = *(const float4*)(B1 + (kt + 1) * BK + octA * 8);
            bb  = *(const float4*)(B1 + (kt + 1) * BK + octA * 8 + 4);
        }
        // ---- wf: 8 direct global loads from W2T (L2-hot), issued early
        bf16x8 wf0[4], wf1[4];
        const __bf16* wkt = wbase + (size_t)kt * 8 * 2048;
#pragma unroll
        for (int f = 0; f < 4; ++f)
            wf0[f] = *(const bf16x8*)(wkt + f * 16 * 8);                 // ks=0
#pragma unroll
        for (int f = 0; f < 4; ++f)
            wf1[f] = *(const bf16x8*)(wkt + 4 * 2048 + f * 16 * 8);      // ks=1
        // ---- h8 -> At[nxt] (waits only on W1: vmcnt leaves wf in flight)
        if (kt + 1 < KIT) {
            bf16x8 hv;
            h8(hv, sv0.x, sv0.y, w0a, w0b, w1a, w1b, ba, bb);
            *(bf16x8*)(An + (octA * 64 + smpA) * 8) = hv;
            h8(hv, sv1.x, sv1.y, w0a, w0b, w1a, w1b, ba, bb);
            *(bf16x8*)(An + (octA * 64 + 32 + smpA) * 8) = hv;
        }
        // ---- ks=0: 4 hf ds_reads + 16 MFMA
        {
            bf16x8 hf[4];
#pragma unroll
            for (int f = 0; f < 4; ++f)
                hf[f] = *(const bf16x8*)(Ac + ((quad * 64) + f * 16 + l15) * 8);
#pragma unroll
            for (int fn = 0; fn < 4; ++fn)
#pragma unroll
                for (int fm = 0; fm < 4; ++fm)
                    acc[fn][fm] = __builtin_amdgcn_mfma_f32_16x16x32_bf16(
                        wf0[fn], hf[fm], acc[fn][fm], 0, 0, 0);
        }
        // ---- ks=1
        {
            bf16x8 hf[4];
#pragma unroll
            for (int f = 0; f < 4; ++f)
                hf[f] = *(const bf16x8*)(Ac + (((4 + quad) * 64) + f * 16 + l15) * 8);
#pragma unroll
            for (int fn = 0; fn < 4; ++fn)
#pragma unroll
                for (int fm = 0; fm < 4; ++fm)
                    acc[fn][fm] = __builtin_amdgcn_mfma_f32_16x16x32_bf16(
                        wf1[fn], hf[fm], acc[fn][fm], 0, 0, 0);
        }
        __syncthreads();   // At[nxt] visible; all At[cur] reads done. VMEM
                           // already consumed -> the vmcnt(0) drain is free.
    }

    // ---- epilogue: relu(acc + b2) -> featL (overlay over At, 32 KiB)
#pragma unroll
    for (int fn = 0; fn < 4; ++fn) {
        const int fcb = wv * 64 + fn * 16 + quad * 4;   // featcol base
        const float4 b2v = *(const float4*)(B2 + slab * 256 + fcb);
        const int o = fcb >> 3, j = fcb & 7;
#pragma unroll
        for (int fm = 0; fm < 4; ++fm) {
            const int smp = fm * 16 + l15;
            const floatx4 v = acc[fn][fm];
            bf16x4 p;
            p[0] = (__bf16)fmaxf(v[0] + b2v.x, 0.f);
            p[1] = (__bf16)fmaxf(v[1] + b2v.y, 0.f);
            p[2] = (__bf16)fmaxf(v[2] + b2v.z, 0.f);
            p[3] = (__bf16)fmaxf(v[3] + b2v.w, 0.f);
            *(bf16x4*)(featL + (o * 64 + smp) * 8 + j) = p;
        }
    }
    __syncthreads();

    // ---- head MFMA: wave wv -> samples wv*16..+15; WHT direct (L2-hot)
    floatx4 hacc[2] = {};
#pragma unroll
    for (int ks2 = 0; ks2 < 8; ++ks2) {
        const bf16x8 fa = *(const bf16x8*)(featL
                             + ((ks2 * 4 + quad) * 64 + wv * 16 + l15) * 8);
#pragma unroll
        for (int t2 = 0; t2 < 2; ++t2) {
            const int r  = t2 * 16 + l15;
            const int og = slab * 32 + ks2 * 4 + quad;
            const bf16x8 wb = *(const bf16x8*)(WHT + (size_t)og * 256 + r * 8);
            hacc[t2] = __builtin_amdgcn_mfma_f32_16x16x32_bf16(
                fa, wb, hacc[t2], 0, 0, 0);
        }
    }

    // ---- atomic scatter: sample = quad*4+reg; emit selected skill's 4 actions
#pragma unroll
    for (int j = 0; j < 4; ++j) {
        const int smp = wv * 16 + quad * 4 + j;
        const int sk  = SK[i0 + smp];
#pragma unroll
        for (int t2 = 0; t2 < 2; ++t2) {
            const int hc = t2 * 16 + l15;
            const int d  = hc - sk * 4;
            if (d >= 0 && d < 4) {
                float v = hacc[t2][j];
                if (slab == 0) v += BH[hc];
                atomicAdd(&OUT[(i0 + smp) * 4 + d], v);
            }
        }
    }
}

extern "C" void kernel_launch(void* const* d_in, const int* in_sizes, int n_in,
                              void* d_out, int out_size, void* d_ws, size_t ws_size,
                              hipStream_t stream) {
    const float* S  = (const float*)d_in[0];
    const int*   SK = (const int*)d_in[1];
    const float* W1 = (const float*)d_in[2];
    const float* B1 = (const float*)d_in[3];
    const float* W2 = (const float*)d_in[4];
    const float* B2 = (const float*)d_in[5];
    const float* WH = (const float*)d_in[6];
    const float* BH = (const float*)d_in[7];

    char* ws = (char*)d_ws;
    __bf16* W2T = (__bf16*)ws;                          // 2 MiB
    __bf16* WHT = (__bf16*)(ws + 2 * 1024 * 1024);      // 64 KiB

    hipLaunchKernelGGL(prep_all, dim3(544), dim3(256), 0, stream,
                       W2, WH, W2T, WHT, (float*)d_out);
    // grid: 1024 sample-groups x 4 slabs; slab = blockIdx>>10 so co-resident
    // blocks share one W2T slab (L2-friendly)
    hipLaunchKernelGGL(policy_main, dim3(4096), dim3(256), 0, stream,
                       S, SK, W1, B1, W2T, B2, WHT, BH, (float*)d_out);
}

// Round 16
// 218.928 us; speedup vs baseline: 2.1512x; 1.0264x over previous
//
#include <hip/hip_runtime.h>

typedef __bf16 bf16x8 __attribute__((ext_vector_type(8)));
typedef __bf16 bf16x4 __attribute__((ext_vector_type(4)));
typedef float  floatx4 __attribute__((ext_vector_type(4)));

#define GLOBAL_AS __attribute__((address_space(1)))
#define LOCAL_AS  __attribute__((address_space(3)))

static constexpr int HID = 1024;
static constexpr int BK  = 64;        // K per tile
static constexpr int KIT = HID / BK;  // 16 K-tiles

__device__ __forceinline__ void h8(bf16x8& d, float s0, float s1,
                                   const float4& w0a, const float4& w0b,
                                   const float4& w1a, const float4& w1b,
                                   const float4& ba,  const float4& bb) {
    d[0] = (__bf16)fmaxf(fmaf(s1, w1a.x, fmaf(s0, w0a.x, ba.x)), 0.f);
    d[1] = (__bf16)fmaxf(fmaf(s1, w1a.y, fmaf(s0, w0a.y, ba.y)), 0.f);
    d[2] = (__bf16)fmaxf(fmaf(s1, w1a.z, fmaf(s0, w0a.z, ba.z)), 0.f);
    d[3] = (__bf16)fmaxf(fmaf(s1, w1a.w, fmaf(s0, w0a.w, ba.w)), 0.f);
    d[4] = (__bf16)fmaxf(fmaf(s1, w1b.x, fmaf(s0, w0b.x, bb.x)), 0.f);
    d[5] = (__bf16)fmaxf(fmaf(s1, w1b.y, fmaf(s0, w0b.y, bb.y)), 0.f);
    d[6] = (__bf16)fmaxf(fmaf(s1, w1b.z, fmaf(s0, w0b.z, bb.z)), 0.f);
    d[7] = (__bf16)fmaxf(fmaf(s1, w1b.w, fmaf(s0, w0b.w, bb.w)), 0.f);
}

// ---------------------------------------------------------------------------
// prep (r11 layouts, byte-identical):
//   [0,256)    zero OUT
//   [256,512)  W2 [K][N] fp32 -> W2T K-octet-major bf16:
//              W2T[(((slab*16+kt)*8+oct)*256+col)*8 + j]
//                = W2[kt*64+oct*8+j][slab*256+col]
//   [512,544)  W_heads -> WHT[(k>>3)*256 + r*8 + (k&7)], r=s*4+a (<20), else 0
// ---------------------------------------------------------------------------
__global__ __launch_bounds__(256)
void prep_all(const float* __restrict__ W2, const float* __restrict__ WH,
              __bf16* __restrict__ W2T, __bf16* __restrict__ WHT,
              float* __restrict__ OUT) {
    int b = blockIdx.x;
    if (b < 256) {
        ((float4*)OUT)[(size_t)b * 256 + threadIdx.x]
            = make_float4(0.f, 0.f, 0.f, 0.f);
        return;
    }
    b -= 256;
    if (b < 256) {
        __shared__ __align__(16) __bf16 tile[64][72];  // [col][k], 16B-aligned rows
        const int bx = b & 15;   // 64-col group
        const int by = b >> 4;   // 64-k group (= kt)
        const int a  = threadIdx.x & 63;
        const int bb = threadIdx.x >> 6;  // 0..3
#pragma unroll
        for (int r = 0; r < 16; ++r) {
            const int k = r * 4 + bb;
            tile[a][k] = (__bf16)W2[(size_t)(by * 64 + k) * HID + bx * 64 + a];
        }
        __syncthreads();
        const int slab = bx >> 2;
#pragma unroll
        for (int p = 0; p < 2; ++p) {
            const int idx = p * 256 + threadIdx.x;   // 0..511
            const int c   = idx & 63;
            const int oct = idx >> 6;                // 0..7
            const bf16x8 v = *(const bf16x8*)&tile[c][oct * 8];
            const int col = (bx & 3) * 64 + c;
            const size_t dst = ((size_t)(slab * KIT + by) * 8 + oct) * 256 + col;
            *(bf16x8*)(W2T + dst * 8) = v;
        }
    } else {
        const int r = b - 256;             // 0..31
        const int s = r >> 2, a = r & 3;
        for (int k = threadIdx.x; k < HID; k += 256) {
            const float v = (r < 20) ? WH[((size_t)s * HID + k) * 4 + a] : 0.f;
            WHT[(size_t)(k >> 3) * 256 + r * 8 + (k & 7)] = (__bf16)v;
        }
    }
}

// ---------------------------------------------------------------------------
// CHAMPION (r11) + T5 s_setprio around the MFMA clusters.
// Regime argument (catalog T5): setprio is null on LOCKSTEP schedules (m190)
// but +4-7% when resident waves sit at DIFFERENT phases (m191). r11 has 3
// independent blocks/CU with no inter-block sync -- at any instant some
// waves are in h8/VMEM phases while others enter their 32-MFMA cluster.
// setprio(1) biases issue arbitration toward the matrix pipe there. Zero
// registers, zero structure change, zero correctness risk.
// Everything else byte-identical to r11 (165.4 us main best measurement).
// ---------------------------------------------------------------------------
__global__ __launch_bounds__(256, 3)
void policy_main(const float* __restrict__ S,  const int* __restrict__ SK,
                 const float* __restrict__ W1, const float* __restrict__ B1,
                 const __bf16* __restrict__ W2T, const float* __restrict__ B2,
                 const __bf16* __restrict__ WHT, const float* __restrict__ BH,
                 float* __restrict__ OUT) {
    __shared__ __align__(16) char smem[32768];
    __bf16* At    = (__bf16*)smem;            // 2 x [8 oct][64 smp][8] = 16 KiB
    __bf16* featL = (__bf16*)smem;            // overlay [32 oct][64 smp][8] = 32K

    const int tid  = threadIdx.x;
    const int lane = tid & 63;
    const int wv   = tid >> 6;       // 0..3  (featcol strip of 64)
    const int l15  = lane & 15;
    const int quad = lane >> 4;
    const int slab = blockIdx.x >> 10;      // 0..3 (256-col slab)
    const int g    = blockIdx.x & 1023;     // sample group
    const size_t i0 = (size_t)g * 64;

    const int octA = wv * 2 + (lane >> 5);  // A-compute k-octet
    const int smpA = lane & 31;             // A-compute sample

    floatx4 acc[4][4] = {};   // [fn featcol-frag][fm sample-frag]

    // ---- prologue: this lane's 2 sample states
    const float2 sv0 = *(const float2*)(S + (i0 + smpA) * 2);
    const float2 sv1 = *(const float2*)(S + (i0 + 32 + smpA) * 2);

    // ---- prologue: compute A[0] -> At buf 0
    {
        const float* wp = W1 + octA * 8;
        const float4 w0a = *(const float4*)(wp);
        const float4 w0b = *(const float4*)(wp + 4);
        const float4 w1a = *(const float4*)(wp + HID);
        const float4 w1b = *(const float4*)(wp + HID + 4);
        const float4 ba  = *(const float4*)(B1 + octA * 8);
        const float4 bb  = *(const float4*)(B1 + octA * 8 + 4);
        bf16x8 hv;
        h8(hv, sv0.x, sv0.y, w0a, w0b, w1a, w1b, ba, bb);
        *(bf16x8*)(At + (octA * 64 + smpA) * 8) = hv;
        h8(hv, sv1.x, sv1.y, w0a, w0b, w1a, w1b, ba, bb);
        *(bf16x8*)(At + (octA * 64 + 32 + smpA) * 8) = hv;
    }
    __syncthreads();   // At[0] visible

    // per-lane W2T fragment base: octet o reads at +o*2048 elems, ks at quad
    const __bf16* wbase = W2T + ((size_t)(slab * KIT) * 8 + quad) * 2048
                        + (wv * 64 + l15) * 8;

#pragma unroll 1
    for (int kt = 0; kt < KIT; ++kt) {
        const __bf16* Ac = At + (kt & 1) * 4096;
        __bf16*       An = At + ((kt + 1) & 1) * 4096;

        // ---- W1/B1 loads for NEXT tile first (oldest in vm queue)
        float4 w0a, w0b, w1a, w1b, ba, bb;
        if (kt + 1 < KIT) {
            const float* wp = W1 + (kt + 1) * BK + octA * 8;
            w0a = *(const float4*)(wp);
            w0b = *(const float4*)(wp + 4);
            w1a = *(const float4*)(wp + HID);
            w1b = *(const float4*)(wp + HID + 4);
            ba  = *(const float4*)(B1 + (kt + 1) * BK + octA * 8);
            bb  = *(const float4*)(B1 + (kt + 1) * BK + octA * 8 + 4);
        }
        // ---- wf: 8 direct global loads from W2T (L2-hot), issued early
        bf16x8 wf0[4], wf1[4];
        const __bf16* wkt = wbase + (size_t)kt * 8 * 2048;
#pragma unroll
        for (int f = 0; f < 4; ++f)
            wf0[f] = *(const bf16x8*)(wkt + f * 16 * 8);                 // ks=0
#pragma unroll
        for (int f = 0; f < 4; ++f)
            wf1[f] = *(const bf16x8*)(wkt + 4 * 2048 + f * 16 * 8);      // ks=1
        // ---- h8 -> At[nxt] (waits only on W1: vmcnt leaves wf in flight)
        if (kt + 1 < KIT) {
            bf16x8 hv;
            h8(hv, sv0.x, sv0.y, w0a, w0b, w1a, w1b, ba, bb);
            *(bf16x8*)(An + (octA * 64 + smpA) * 8) = hv;
            h8(hv, sv1.x, sv1.y, w0a, w0b, w1a, w1b, ba, bb);
            *(bf16x8*)(An + (octA * 64 + 32 + smpA) * 8) = hv;
        }
        // ---- ks=0: 4 hf ds_reads + 16 MFMA (setprio'd cluster)
        {
            bf16x8 hf[4];
#pragma unroll
            for (int f = 0; f < 4; ++f)
                hf[f] = *(const bf16x8*)(Ac + ((quad * 64) + f * 16 + l15) * 8);
            __builtin_amdgcn_s_setprio(1);
#pragma unroll
            for (int fn = 0; fn < 4; ++fn)
#pragma unroll
                for (int fm = 0; fm < 4; ++fm)
                    acc[fn][fm] = __builtin_amdgcn_mfma_f32_16x16x32_bf16(
                        wf0[fn], hf[fm], acc[fn][fm], 0, 0, 0);
            __builtin_amdgcn_s_setprio(0);
        }
        // ---- ks=1 (setprio'd cluster)
        {
            bf16x8 hf[4];
#pragma unroll
            for (int f = 0; f < 4; ++f)
                hf[f] = *(const bf16x8*)(Ac + (((4 + quad) * 64) + f * 16 + l15) * 8);
            __builtin_amdgcn_s_setprio(1);
#pragma unroll
            for (int fn = 0; fn < 4; ++fn)
#pragma unroll
                for (int fm = 0; fm < 4; ++fm)
                    acc[fn][fm] = __builtin_amdgcn_mfma_f32_16x16x32_bf16(
                        wf1[fn], hf[fm], acc[fn][fm], 0, 0, 0);
            __builtin_amdgcn_s_setprio(0);
        }
        __syncthreads();   // At[nxt] visible; all At[cur] reads done. VMEM
                           // already consumed -> the vmcnt(0) drain is free.
    }

    // ---- epilogue: relu(acc + b2) -> featL (overlay over At, 32 KiB)
#pragma unroll
    for (int fn = 0; fn < 4; ++fn) {
        const int fcb = wv * 64 + fn * 16 + quad * 4;   // featcol base
        const float4 b2v = *(const float4*)(B2 + slab * 256 + fcb);
        const int o = fcb >> 3, j = fcb & 7;
#pragma unroll
        for (int fm = 0; fm < 4; ++fm) {
            const int smp = fm * 16 + l15;
            const floatx4 v = acc[fn][fm];
            bf16x4 p;
            p[0] = (__bf16)fmaxf(v[0] + b2v.x, 0.f);
            p[1] = (__bf16)fmaxf(v[1] + b2v.y, 0.f);
            p[2] = (__bf16)fmaxf(v[2] + b2v.z, 0.f);
            p[3] = (__bf16)fmaxf(v[3] + b2v.w, 0.f);
            *(bf16x4*)(featL + (o * 64 + smp) * 8 + j) = p;
        }
    }
    __syncthreads();

    // ---- head MFMA: wave wv -> samples wv*16..+15; WHT direct (L2-hot)
    floatx4 hacc[2] = {};
#pragma unroll
    for (int ks2 = 0; ks2 < 8; ++ks2) {
        const bf16x8 fa = *(const bf16x8*)(featL
                             + ((ks2 * 4 + quad) * 64 + wv * 16 + l15) * 8);
#pragma unroll
        for (int t2 = 0; t2 < 2; ++t2) {
            const int r  = t2 * 16 + l15;
            const int og = slab * 32 + ks2 * 4 + quad;
            const bf16x8 wb = *(const bf16x8*)(WHT + (size_t)og * 256 + r * 8);
            hacc[t2] = __builtin_amdgcn_mfma_f32_16x16x32_bf16(
                fa, wb, hacc[t2], 0, 0, 0);
        }
    }

    // ---- atomic scatter: sample = quad*4+reg; emit selected skill's 4 actions
#pragma unroll
    for (int j = 0; j < 4; ++j) {
        const int smp = wv * 16 + quad * 4 + j;
        const int sk  = SK[i0 + smp];
#pragma unroll
        for (int t2 = 0; t2 < 2; ++t2) {
            const int hc = t2 * 16 + l15;
            const int d  = hc - sk * 4;
            if (d >= 0 && d < 4) {
                float v = hacc[t2][j];
                if (slab == 0) v += BH[hc];
                atomicAdd(&OUT[(i0 + smp) * 4 + d], v);
            }
        }
    }
}

extern "C" void kernel_launch(void* const* d_in, const int* in_sizes, int n_in,
                              void* d_out, int out_size, void* d_ws, size_t ws_size,
                              hipStream_t stream) {
    const float* S  = (const float*)d_in[0];
    const int*   SK = (const int*)d_in[1];
    const float* W1 = (const float*)d_in[2];
    const float* B1 = (const float*)d_in[3];
    const float* W2 = (const float*)d_in[4];
    const float* B2 = (const float*)d_in[5];
    const float* WH = (const float*)d_in[6];
    const float* BH = (const float*)d_in[7];

    char* ws = (char*)d_ws;
    __bf16* W2T = (__bf16*)ws;                          // 2 MiB
    __bf16* WHT = (__bf16*)(ws + 2 * 1024 * 1024);      // 64 KiB

    hipLaunchKernelGGL(prep_all, dim3(544), dim3(256), 0, stream,
                       W2, WH, W2T, WHT, (float*)d_out);
    // grid: 1024 sample-groups x 4 slabs; slab = blockIdx>>10 so co-resident
    // blocks share one W2T slab (L2-friendly)
    hipLaunchKernelGGL(policy_main, dim3(4096), dim3(256), 0, stream,
                       S, SK, W1, B1, W2T, B2, WHT, BH, (float*)d_out);
}